// Round 13
// baseline (108.629 us; speedup 1.0000x reference)
//
#include <hip/hip_runtime.h>

// VQ-VAE forward + EMA update, MI355X.
// Sizes fixed by the reference: B=64, C=D=8, H=W=64, K=512.
constexpr int Kc   = 512;
constexpr int Dc   = 8;
constexpr int HWc  = 4096;            // 64*64
constexpr int CHWc = Dc * HWc;        // 32768
constexpr int Mc   = 64 * HWc;        // 262144 vectors
constexpr int TOTALc = Mc * Dc;       // 2097152 elements of z / z_q

// 8 replica accumulators (one per XCD via blockIdx&7) to cut atomic contention.
constexpr int REP      = 8;
constexpr int RSTRIDE  = 4616;        // 512 counts + 4096 sums + 1 loss + 7 pad
constexpr int ACC_FLOATS = REP * RSTRIDE;   // 36928 floats (~148 KB)
// d_ws float layout:
//   [0 .. ACC_FLOATS)            replica accumulators (counts | sums | loss | pad) x8
//   [ACC_FLOATS .. +512)         e_sq[k]

typedef float v2f  __attribute__((ext_vector_type(2)));
typedef unsigned long long ull;
typedef ull  u64x4 __attribute__((ext_vector_type(4)));

__global__ __launch_bounds__(256) void vq_prep(const float* __restrict__ cb,
                                               float* __restrict__ ws) {
    const int tid = blockIdx.x * 256 + threadIdx.x;
    float4* w4 = (float4*)ws;
    for (int i = tid; i < ACC_FLOATS / 4; i += gridDim.x * 256)
        w4[i] = float4{0.f, 0.f, 0.f, 0.f};
    if (blockIdx.x == 0) {
        for (int k = threadIdx.x; k < Kc; k += 256) {
            float s = 0.f;
#pragma unroll
            for (int c = 0; c < Dc; ++c) {
                const float e = cb[k * Dc + c];
                s = fmaf(e, e, s);
            }
            ws[ACC_FLOATS + k] = s;
        }
    }
}

// 1024 blocks x 512 threads; block owns 256 consecutive vectors.
// 8 k-groups x 1 wave; lane l scores V=4 vectors (l,l+64,l+128,l+192) via
// v_pk_fma_f32 (codebook pair in SGPR pair, lo/hi broadcast via op_sel).
// ASM-SCHEDULED SMEM PIPELINE, SGPR-budget-correct (r12 crashed: 2x36-dword
// sets = 116 SGPR > 102 limit). Granule = 2 codes: set = 2x s_load_dwordx8
// (rows) + s_load_dwordx2 (esq pair) = 18 SGPR; 2 sets + ~44 overhead = 80
// = r11's measured allocation. Schedule per step (32 steps/wave):
//   [s_waitcnt lgkmcnt(0)]   <- drains the ONE outstanding set, aged one
//   [sched_barrier(0)]          compute phase (~184 cyc)
//   [issue next set]         <- volatile asm s_loads
//   [sched_barrier(0)]
//   [compute 2 codes]        <- volatile pk_fma blocks
// Convoy model being tested: VALUBusy 59-62% == single-wave duty C/(C+L),
// L~255cyc; all 8 waves/SIMD stall in lockstep. With the wait BEFORE the
// issue, stall = max(0, L-C) = ~71cyc -> duty ~72%. r11 proved HIP-level
// prefetch can't do this (compiler puts lgkmcnt(0) after next-issue);
// rule #18: sched_barrier(0) right after the wait stops register-op hoist.
// Math BIT-IDENTICAL to r0/r4/r8: a = esq[k]; a += zz[c]*e[c], c ascending;
// strict-< first-index-wins; groups ascending in k.
__global__ __launch_bounds__(512, 8) void vq_main(const float* __restrict__ z,
                                                  const float* __restrict__ cb,
                                                  const float* __restrict__ esq,
                                                  float* __restrict__ ws,
                                                  float* __restrict__ zq) {
    __shared__ float s_mn[8][256];         // 8 KB
    __shared__ int   s_im[8][256];         // 8 KB
    __shared__ float s_counts[Kc];         // 2 KB
    __shared__ float s_sums[Kc * Dc];      // 16 KB
    __shared__ float s_loss;

    const int t = threadIdx.x;
    for (int i = t; i < Kc; i += 512) s_counts[i] = 0.f;
    for (int i = t; i < Kc * Dc; i += 512) s_sums[i] = 0.f;
    if (t == 0) s_loss = 0.f;

    const int l = t & 63;
    // wave-uniform k-group; readfirstlane keeps codebook addresses provably
    // uniform -> SGPR pointers for the asm s_loads.
    const int g  = __builtin_amdgcn_readfirstlane(t >> 6);   // 0..7
    const int k0 = g << 6;

    const int base = blockIdx.x * 256;        // 256-aligned -> one batch idx
    const int b  = base >> 12;
    const int n0 = (base & (HWc - 1)) + l;    // +64*j below never wraps 4096
    const float* zb = z + b * CHWc + n0;

    // zzA[c] = (-2*z[vec l][c], -2*z[vec l+64][c]); zzB: vecs l+128, l+192.
    v2f zzA[Dc], zzB[Dc];
#pragma unroll
    for (int c = 0; c < Dc; ++c) {
        zzA[c] = v2f{-2.0f * zb[c * HWc],       -2.0f * zb[c * HWc + 64]};
        zzB[c] = v2f{-2.0f * zb[c * HWc + 128], -2.0f * zb[c * HWc + 192]};
    }
    // Pin zz VGPR-resident (r9: safe/neutral); keeps rematerialized loads
    // from landing between the volatile asm blocks.
    asm("" : "+v"(zzA[0]), "+v"(zzA[1]), "+v"(zzA[2]), "+v"(zzA[3]),
             "+v"(zzA[4]), "+v"(zzA[5]), "+v"(zzA[6]), "+v"(zzA[7]),
             "+v"(zzB[0]), "+v"(zzB[1]), "+v"(zzB[2]), "+v"(zzB[3]),
             "+v"(zzB[4]), "+v"(zzB[5]), "+v"(zzB[6]), "+v"(zzB[7]));

    const float* cbg = cb + (k0 << 3);        // this group's 64 rows (2 KB)
    const float* eqg = esq + k0;

    float mn0 = 3.4e38f, mn1 = 3.4e38f, mn2 = 3.4e38f, mn3 = 3.4e38f;
    int   i0 = k0, i1 = k0, i2 = k0, i3 = k0;

// issue one 2-code set: 2 rows (2x s_load_dwordx8) + esq pair (dwordx2).
// Byte offsets are wave-uniform SGPR values (SALU-computed).
#define SLOAD(R0, R1, EV, ROFF, EOFF)                                  \
    asm volatile("s_load_dwordx8 %0, %3, %5\n\t"                       \
                 "s_load_dwordx8 %1, %3, %6\n\t"                       \
                 "s_load_dwordx2 %2, %4, %7"                           \
                 : "=s"(R0), "=s"(R1), "=s"(EV)                        \
                 : "s"(cbg), "s"(eqg),                                 \
                   "s"(ROFF), "s"((ROFF) + 32), "s"(EOFF))

// one code: 16 packed fma + argmin update. op_sel_hi:[1,0,1] broadcasts the
// LOW dword of the sgpr pair (e[2p]); op_sel:[0,1,0] (default op_sel_hi)
// broadcasts the HIGH dword (e[2p+1]). First step folds the {ev,ev} addend
// directly (same value & rounding as init-then-fma). Chain: c ascending.
#define PKSTEP(Q, P0, P1)                                              \
    asm volatile(                                                      \
        "v_pk_fma_f32 %0, %2, %4, %0 op_sel_hi:[1,0,1]\n\t"            \
        "v_pk_fma_f32 %1, %3, %4, %1 op_sel_hi:[1,0,1]\n\t"            \
        "v_pk_fma_f32 %0, %5, %4, %0 op_sel:[0,1,0]\n\t"               \
        "v_pk_fma_f32 %1, %6, %4, %1 op_sel:[0,1,0]"                   \
        : "+v"(aA), "+v"(aB)                                           \
        : "v"(zzA[P0]), "v"(zzB[P0]), "s"(Q), "v"(zzA[P1]), "v"(zzB[P1]))

#define CODE1(ROW, EVF, KK)                                            \
    {                                                                  \
        const float ev_ = (EVF);                                       \
        const v2f vev2 = {ev_, ev_};                                   \
        v2f aA, aB;                                                    \
        asm volatile(                                                  \
            "v_pk_fma_f32 %0, %2, %4, %5 op_sel_hi:[1,0,1]\n\t"        \
            "v_pk_fma_f32 %1, %3, %4, %5 op_sel_hi:[1,0,1]\n\t"        \
            "v_pk_fma_f32 %0, %6, %4, %0 op_sel:[0,1,0]\n\t"           \
            "v_pk_fma_f32 %1, %7, %4, %1 op_sel:[0,1,0]"               \
            : "=&v"(aA), "=&v"(aB)                                     \
            : "v"(zzA[0]), "v"(zzB[0]), "s"((ROW).x), "v"(vev2),       \
              "v"(zzA[1]), "v"(zzB[1]));                               \
        PKSTEP((ROW).y, 2, 3);                                         \
        PKSTEP((ROW).z, 4, 5);                                         \
        PKSTEP((ROW).w, 6, 7);                                         \
        const float a0 = aA.x, a1 = aA.y, a2 = aB.x, a3 = aB.y;        \
        bool c_;                                                       \
        c_ = a0 < mn0; mn0 = c_ ? a0 : mn0; i0 = c_ ? (KK) : i0;       \
        c_ = a1 < mn1; mn1 = c_ ? a1 : mn1; i1 = c_ ? (KK) : i1;       \
        c_ = a2 < mn2; mn2 = c_ ? a2 : mn2; i2 = c_ ? (KK) : i2;       \
        c_ = a3 < mn3; mn3 = c_ ? a3 : mn3; i3 = c_ ? (KK) : i3;       \
    }

// one pipeline step: wait(current set, aged one phase) -> issue(next set
// at byte offsets ro/eo, clamped at the tail) -> compute 2 codes.
#define PIPE_STEP(C0, C1, CEV, N0, N1, NEV, KK)                        \
    asm volatile("s_waitcnt lgkmcnt(0)");                              \
    __builtin_amdgcn_sched_barrier(0);                                 \
    {                                                                  \
        const int ro_ = ro > 1984 ? 1984 : ro;                         \
        const int eo_ = eo > 248  ? 248  : eo;                         \
        SLOAD(N0, N1, NEV, ro_, eo_);                                  \
        ro += 64; eo += 8;                                             \
    }                                                                  \
    __builtin_amdgcn_sched_barrier(0);                                 \
    CODE1(C0, (CEV)[0], KK);                                           \
    CODE1(C1, (CEV)[1], (KK) + 1);

    u64x4 A0, A1, B0, B1;
    v2f   Aev, Bev;
    int ro = 0, eo = 0;
    SLOAD(A0, A1, Aev, 0, 0);                 // prologue: set 0
    ro = 64; eo = 8;                          // next to issue: set 1
    int kk = k0;
#pragma unroll 1
    for (int hs = 0; hs < 16; ++hs) {
        // step 2hs: consume A (set 2hs), issue set 2hs+1 into B
        PIPE_STEP(A0, A1, Aev, B0, B1, Bev, kk);
        // step 2hs+1: consume B, issue set 2hs+2 into A (clamped at tail)
        PIPE_STEP(B0, B1, Bev, A0, A1, Aev, kk + 2);
        kk += 4;
    }

#undef PIPE_STEP
#undef CODE1
#undef PKSTEP
#undef SLOAD

    s_mn[g][l]       = mn0;  s_im[g][l]       = i0;
    s_mn[g][l +  64] = mn1;  s_im[g][l +  64] = i1;
    s_mn[g][l + 128] = mn2;  s_im[g][l + 128] = i2;
    s_mn[g][l + 192] = mn3;  s_im[g][l + 192] = i3;
    __syncthreads();

    if (t < 256) {
        const int v = t;                      // block-local vector id
        float mn = s_mn[0][v];
        int   im = s_im[0][v];
#pragma unroll
        for (int gg = 1; gg < 8; ++gg) {
            const float m2 = s_mn[gg][v];     // groups ascending in k:
            const int   j2 = s_im[gg][v];     // strict < keeps first index
            const bool  c2 = m2 < mn;
            mn = c2 ? m2 : mn;
            im = c2 ? j2 : im;
        }

        // Gather old-codebook row (16 KB table, L1-hot; 32B/lane).
        const float4* cb4 = (const float4*)cb;
        const float4 qa = cb4[im * 2], qb = cb4[im * 2 + 1];
        const float q[Dc] = {qa.x, qa.y, qa.z, qa.w, qb.x, qb.y, qb.z, qb.w};

        const int nv = (base & (HWc - 1)) + v;
        const float* zv = z + b * CHWc + nv;  // re-read z (L1/L2-hot)
        float* zqv = zq + b * CHWc + nv;
        float lsum = 0.f;
        float zr[Dc];
#pragma unroll
        for (int c = 0; c < Dc; ++c) {
            zr[c] = zv[c * HWc];
            zqv[c * HWc] = q[c];              // coalesced stores
            const float d = q[c] - zr[c];
            lsum = fmaf(d, d, lsum);
        }

        // Per-block LDS histogram (ds_add_f32) — coalesces same-index hits.
        unsafeAtomicAdd(&s_counts[im], 1.0f);
#pragma unroll
        for (int c = 0; c < Dc; ++c)
            unsafeAtomicAdd(&s_sums[im * Dc + c], zr[c]);
        unsafeAtomicAdd(&s_loss, lsum);
    }
    __syncthreads();

    // Flush non-zero bins to this block's replica accumulator (all 512 thr).
    float* acc = ws + (blockIdx.x & (REP - 1)) * RSTRIDE;
    for (int i = t; i < Kc; i += 512) {
        const float val = s_counts[i];
        if (val != 0.f) unsafeAtomicAdd(&acc[i], val);
    }
    for (int i = t; i < Kc * Dc; i += 512) {
        const float val = s_sums[i];
        if (val != 0.f) unsafeAtomicAdd(&acc[512 + i], val);
    }
    if (t == 0) unsafeAtomicAdd(&acc[4608], s_loss);
}

// 9 blocks: every block redundantly recomputes the (cheap) counts/cs phase;
// block 0 writes cs + loss, blocks 1..8 each handle 512 of the 4096 K*D
// elements.
__global__ __launch_bounds__(512) void vq_final(const float* __restrict__ ws,
                                                const float* __restrict__ ema_cs,
                                                const float* __restrict__ ema_w,
                                                float* __restrict__ out) {
    constexpr float DEC  = 0.99f;
    constexpr float OMD  = (float)(1.0 - 0.99);      // matches jnp f32 cast
    constexpr float EPSf = 1e-5f;
    constexpr float KEPS = (float)(512 * 1e-5);      // 0.00512
    __shared__ float red[512];
    __shared__ float s_cs[512];

    const int t = threadIdx.x;
    // counts: lane-consecutive reads per replica (coalesced)
    float cnt = 0.f;
#pragma unroll
    for (int r = 0; r < REP; ++r) cnt += ws[r * RSTRIDE + t];
    const float ncs = ema_cs[t] * DEC + cnt * OMD;
    red[t] = ncs;
    __syncthreads();
    for (int s = 256; s > 0; s >>= 1) {
        if (t < s) red[t] += red[t + s];
        __syncthreads();
    }
    const float n  = red[0];
    const float cs = (ncs + EPSf) / (n + KEPS) * n;
    s_cs[t] = cs;

    float* out_loss = out + TOTALc;          // [1]
    float* out_cb   = out + TOTALc + 1;      // [K*D]
    float* out_cs   = out_cb + Kc * Dc;      // [K]
    float* out_nw   = out_cs + Kc;           // [K*D]

    __syncthreads();

    const int blk = blockIdx.x;
    if (blk == 0) {
        out_cs[t] = cs;
        if (t == 0) {
            float ls = 0.f;
#pragma unroll
            for (int r = 0; r < REP; ++r) ls += ws[r * RSTRIDE + 4608];
            out_loss[0] = ls * (1.0f / 2097152.0f);  // /2^21 exact
        }
    } else {
        const int e = (blk - 1) * 512 + t;   // one element per thread
        float sm = 0.f;
#pragma unroll
        for (int r = 0; r < REP; ++r) sm += ws[r * RSTRIDE + 512 + e];
        const float nw = ema_w[e] * DEC + sm * OMD;
        out_nw[e] = nw;
        out_cb[e] = nw / s_cs[e >> 3];
    }
}

extern "C" void kernel_launch(void* const* d_in, const int* in_sizes, int n_in,
                              void* d_out, int out_size, void* d_ws, size_t ws_size,
                              hipStream_t stream) {
    const float* z      = (const float*)d_in[0];
    const float* cb     = (const float*)d_in[1];
    const float* ema_cs = (const float*)d_in[2];
    const float* ema_w  = (const float*)d_in[3];
    float* out = (float*)d_out;
    float* ws  = (float*)d_ws;

    vq_prep<<<32, 256, 0, stream>>>(cb, ws);
    vq_main<<<Mc / 256, 512, 0, stream>>>(z, cb, ws + ACC_FLOATS, ws, out);
    vq_final<<<9, 512, 0, stream>>>(ws, ema_cs, ema_w, out);
}